// Round 9
// baseline (648.489 us; speedup 1.0000x reference)
//
#include <hip/hip_runtime.h>
#include <cstddef>

// ---------------------------------------------------------------------------
// SpiralAutoencoder on MI355X — round 19:
//  * Partial-buffer stores (d0/d1/d2) + reduce loads -> NON-TEMPORAL: the
//    20MB of write-allocate traffic was evicting A/B panels from L2 (d0
//    FETCH 60.8MB vs 23MB unique). L2 now holds operands only.
//  * All 11 tiny weight-prep launches fused into ONE prep_weights kernel
//    (c3/c4 frag swizzle folds f2bf inline — bitwise-identical permutation).
//    Weights live in bufA tail [10,160,000..) — never clobbered (audited).
// ---------------------------------------------------------------------------

#define BATCH 64
#define SPK 12  // spiral length

typedef __attribute__((ext_vector_type(8))) short bf16x8;
typedef __attribute__((ext_vector_type(4))) short bf16x4;
typedef __attribute__((ext_vector_type(4))) float f32x4;

__device__ __forceinline__ unsigned short f2bf(float x) {
    union { float f; unsigned int u; } v; v.f = x;
    unsigned int r = v.u + 0x7FFF + ((v.u >> 16) & 1);  // RNE
    return (unsigned short)(r >> 16);
}

// ---------------------------------------------------------------------------
// prep_weights: ALL weight-side conversions/pads/swizzles in one launch.
// ---------------------------------------------------------------------------
__global__ __launch_bounds__(256) void prep_weights_kernel(
    const float* __restrict__ enc_w0, const float* __restrict__ enc_w1,
    const float* __restrict__ enc_w2, const float* __restrict__ enc_w3,
    const float* __restrict__ dec_w0, const float* __restrict__ dec_w1,
    const float* __restrict__ dec_w2, const float* __restrict__ dec_w3,
    const float* __restrict__ dec_w4, const float* __restrict__ dec_b4,
    float* __restrict__ WpE0, unsigned short* __restrict__ Wb_e1,
    unsigned short* __restrict__ Wb_c2, unsigned short* __restrict__ Wb_e2,
    unsigned short* __restrict__ Wb_e3, unsigned short* __restrict__ Wb_c0,
    unsigned short* __restrict__ Wb_c1, unsigned short* __restrict__ Wfs_c3,
    unsigned short* __restrict__ Wfs_c4, float* __restrict__ BpC4)
{
    int i = blockIdx.x * 256 + threadIdx.x;
    if (i < 1024) {                       // e0 W pad (fp32, F 3->4, K 12->16)
        int o = i >> 6, kf = i & 63, k = kf >> 2, f = kf & 3;
        WpE0[i] = (f < 3 && k < 12) ? enc_w0[o * 36 + k * 3 + f] : 0.f;
        return;
    }
    i -= 1024;
    if (i < 6144)  { Wb_e1[i] = f2bf(enc_w1[i]); return; }   // [32][192]
    i -= 6144;
    if (i < 12288) { Wb_c2[i] = f2bf(dec_w2[i]); return; }   // [32][384]
    i -= 12288;
    if (i < 24576) { Wb_e2[i] = f2bf(enc_w2[i]); return; }   // [64][384]
    i -= 24576;
    if (i < 98304) { Wb_e3[i] = f2bf(enc_w3[i]); return; }   // [128][768]
    i -= 98304;
    if (i < 98304) { Wb_c0[i] = f2bf(dec_w0[i]); return; }   // [64][1536]
    i -= 98304;
    if (i < 24576) { Wb_c1[i] = f2bf(dec_w1[i]); return; }   // [32][768]
    i -= 24576;
    if (i < 6144) {                       // c3 W frag-swizzle (KF=384)
        int j = i & 7, lane = (i >> 3) & 63, s = i >> 9;
        int l15 = lane & 15, quad = (lane >> 4) & 3;
        Wfs_c3[i] = f2bf(dec_w3[l15 * 384 + s * 32 + quad * 8 + j]);
        return;
    }
    i -= 6144;
    if (i < 3072) {                       // c4 W pad(3->16) + frag (KF=192)
        int j = i & 7, lane = (i >> 3) & 63, s = i >> 9;
        int l15 = lane & 15, quad = (lane >> 4) & 3;
        Wfs_c4[i] = (l15 < 3) ? f2bf(dec_w4[l15 * 192 + s * 32 + quad * 8 + j])
                              : (unsigned short)0;
        return;
    }
    i -= 3072;
    if (i < 16) BpC4[i] = (i < 3) ? dec_b4[i] : 0.f;
}
#define PREP_TOTAL (1024 + 6144 + 12288 + 24576 + 98304 + 98304 + 24576 + 6144 + 3072 + 16)

// ---------------------------------------------------------------------------
// Sum nparts fp32 partial buffers (stride ps) -> bf16. Non-temporal loads.
// ---------------------------------------------------------------------------
__global__ __launch_bounds__(256) void reducep_bf16_kernel(
    const float* __restrict__ P, size_t ps, unsigned short* __restrict__ out,
    int n8, int nparts)
{
    int i = blockIdx.x * 256 + threadIdx.x;
    if (i < n8) {
        size_t base = (size_t)i * 8;
        bf16x8 r;
#pragma unroll
        for (int j = 0; j < 8; ++j) {
            float v = __builtin_nontemporal_load(&P[base + j]);
            for (int p = 1; p < nparts; ++p)
                v += __builtin_nontemporal_load(&P[(size_t)p * ps + base + j]);
            r[j] = (short)f2bf(v);
        }
        *(bf16x8*)(out + base) = r;
    }
}

// ---------------------------------------------------------------------------
// fp32 [M][K] -> bf16 [Mp][Kp] with zero padding.
// ---------------------------------------------------------------------------
__global__ __launch_bounds__(256) void a_bf16_pad_kernel(
    const float* __restrict__ A, unsigned short* __restrict__ Ap,
    int M, int K, int Kp, int total)
{
    int i = blockIdx.x * 256 + threadIdx.x;
    if (i >= total) return;
    int kp8 = Kp >> 3;
    int m = i / kp8;
    int k0 = (i - m * kp8) * 8;
    bf16x8 r;
    if (m < M) {
        const float* src = A + (size_t)m * K + k0;
#pragma unroll
        for (int j = 0; j < 8; ++j) {
            float v = (k0 + j < K) ? src[j] : 0.f;
            r[j] = (short)f2bf(v);
        }
    } else {
#pragma unroll
        for (int j = 0; j < 8; ++j) r[j] = 0;
    }
    *(bf16x8*)(Ap + (size_t)m * Kp + k0) = r;
}

// ---------------------------------------------------------------------------
// conv_cmfma: O=16 spiral conv, row-coalesced gather. c3/c4.
// ---------------------------------------------------------------------------
template<int LOGF, int OBF16>
__global__ __launch_bounds__(64, 4) void conv_cmfma_kernel(
    const unsigned short* __restrict__ x, const int* __restrict__ S,
    const unsigned short* __restrict__ Wfs, const float* __restrict__ bias,
    void* __restrict__ yv, int Nv, int elu_flag, int swz)
{
    constexpr int F     = 1 << LOGF;
    constexpr int KF    = SPK * F;
    constexpr int NS    = KF / 32;
    constexpr int RPADu = (LOGF == 5) ? 40 : 24;
    __shared__ unsigned short Gs[12 * 16 * RPADu];

    const int lane = threadIdx.x;
    const int l15  = lane & 15;
    const int quad = (lane >> 4) & 3;

    int bx = blockIdx.x, bz = blockIdx.z;
    if (swz) {
        const int gx = gridDim.x;
        const int total = gx * gridDim.z;
        int bid = bx + gx * bz;
        const int chunk = total >> 3;
        int sid = (bid & 7) * chunk + (bid >> 3);
        bx = sid % gx;
        bz = sid / gx;
    }
    const int n0 = bx * 16;
    const int b  = bz;
    const size_t xb = (size_t)b * Nv;

    int4 sv;
    {
        int g = lane >> 4; if (g > 2) g = 2;
        int n = n0 + l15; if (n >= Nv) n = 0;
        sv = *(const int4*)(S + n * SPK + g * 4);
    }

    if constexpr (LOGF == 5) {
        const int grow = lane >> 2, gchk = lane & 3;
#pragma unroll
        for (int k = 0; k < 12; ++k) {
            int sel = ((k >> 2) << 4) | grow;
            int comp = k & 3;
            int src = (comp == 0) ? __shfl(sv.x, sel)
                    : (comp == 1) ? __shfl(sv.y, sel)
                    : (comp == 2) ? __shfl(sv.z, sel)
                                  : __shfl(sv.w, sel);
            bf16x8 v = *(const bf16x8*)(x + ((xb + src) << 5) + gchk * 8);
            *(bf16x8*)&Gs[k * 16 * RPADu + grow * RPADu + gchk * 8] = v;
        }
    } else {
        const int khalf = lane >> 5, grow = (lane >> 1) & 15, gchk = lane & 1;
#pragma unroll
        for (int g = 0; g < 6; ++g) {
            int k0 = 2 * g;
            int sel0 = ((k0 >> 2) << 4) | grow;
            int sel1 = (((k0 + 1) >> 2) << 4) | grow;
            int s0 = ((k0 & 3) == 0) ? __shfl(sv.x, sel0) : __shfl(sv.z, sel0);
            int s1 = (((k0 + 1) & 3) == 1) ? __shfl(sv.y, sel1) : __shfl(sv.w, sel1);
            int src = khalf ? s1 : s0;
            int k   = k0 + khalf;
            bf16x8 v = *(const bf16x8*)(x + ((xb + src) << 4) + gchk * 8);
            *(bf16x8*)&Gs[k * 16 * RPADu + grow * RPADu + gchk * 8] = v;
        }
    }

    f32x4 acc0 = (f32x4){0.f, 0.f, 0.f, 0.f};
    f32x4 acc1 = (f32x4){0.f, 0.f, 0.f, 0.f};
#pragma unroll
    for (int s = 0; s < NS; ++s) {
        int kf = s * 32 + quad * 8;
        int k  = kf >> LOGF;
        int f  = kf & (F - 1);
        bf16x8 a = *(const bf16x8*)&Gs[k * 16 * RPADu + l15 * RPADu + f];
        bf16x8 w = *(const bf16x8*)(Wfs + (s * 64 + lane) * 8);
        if (s & 1) acc1 = __builtin_amdgcn_mfma_f32_16x16x32_bf16(a, w, acc1, 0, 0, 0);
        else       acc0 = __builtin_amdgcn_mfma_f32_16x16x32_bf16(a, w, acc0, 0, 0, 0);
    }

    float bv = bias[l15];
#pragma unroll
    for (int reg = 0; reg < 4; ++reg) {
        int nn = n0 + quad * 4 + reg;
        if (nn >= Nv) continue;
        float v = acc0[reg] + acc1[reg] + bv;
        if (elu_flag && v <= 0.f) v = expm1f(v);
        if (nn == Nv - 1) v = 0.f;
        size_t off = ((size_t)b * Nv + nn) * 16 + l15;
        if (OBF16) ((unsigned short*)yv)[off] = f2bf(v);
        else       ((float*)yv)[off] = v;
    }
}

// ---------------------------------------------------------------------------
// conv_wmfma: direct-gather wave kernel (small levels). e2/e3/c0/c1.
// ---------------------------------------------------------------------------
template<int LOGF, int OBF16>
__global__ __launch_bounds__(64) void conv_wmfma_kernel(
    const unsigned short* __restrict__ x, const int* __restrict__ S,
    const unsigned short* __restrict__ Wb, const float* __restrict__ bias,
    void* __restrict__ yv, int Nv, int O, int elu_flag, int swz)
{
    constexpr int F  = 1 << LOGF;
    constexpr int KF = SPK * F;
    constexpr int NS = KF / 32;
    const int lane = threadIdx.x;
    const int l15  = lane & 15;
    const int quad = lane >> 4;

    int bx = blockIdx.x, by = blockIdx.y, bz = blockIdx.z;
    if (swz) {
        const int gx = gridDim.x, gy = gridDim.y;
        const int total = gx * gy * gridDim.z;
        int bid = bx + gx * (by + gy * bz);
        const int chunk = total >> 3;
        int sid = (bid & 7) * chunk + (bid >> 3);
        bx = sid % gx; sid /= gx;
        by = sid % gy;
        bz = sid / gy;
    }

    const int n0   = bx * 16;
    const int o    = by * 16 + l15;
    const int b    = bz;
    const size_t xb = (size_t)b * Nv;

    const int n  = n0 + l15;
    const int ng = (n < Nv) ? n : 0;
    const unsigned short* wrow = Wb + (size_t)o * KF;

    f32x4 acc0 = (f32x4){0.f, 0.f, 0.f, 0.f};
    f32x4 acc1 = (f32x4){0.f, 0.f, 0.f, 0.f};
#pragma unroll
    for (int s = 0; s < NS; ++s) {
        int kf  = s * 32 + quad * 8;
        int k   = kf >> LOGF;
        int f   = kf & (F - 1);
        int src = S[ng * SPK + k];
        bf16x8 a = *(const bf16x8*)(x + ((xb + src) << LOGF) + f);
        bf16x8 w = *(const bf16x8*)(wrow + kf);
        if (s & 1) acc1 = __builtin_amdgcn_mfma_f32_16x16x32_bf16(a, w, acc1, 0, 0, 0);
        else       acc0 = __builtin_amdgcn_mfma_f32_16x16x32_bf16(a, w, acc0, 0, 0, 0);
    }
    float bv = bias[o];
#pragma unroll
    for (int reg = 0; reg < 4; ++reg) {
        int nn = n0 + quad * 4 + reg;
        if (nn >= Nv) continue;
        float v = acc0[reg] + acc1[reg] + bv;
        if (elu_flag && v <= 0.f) v = expm1f(v);
        if (nn == Nv - 1) v = 0.f;
        size_t off = ((size_t)b * Nv + nn) * O + o;
        if (OBF16) ((unsigned short*)yv)[off] = f2bf(v);
        else       ((float*)yv)[off] = v;
    }
}

// ---------------------------------------------------------------------------
// conv_mfma32: O=32 spiral conv via MFMA. W pre-converted bf16. e1/c2.
// ---------------------------------------------------------------------------
template<int LOGF>
__global__ __launch_bounds__(256) void conv_mfma32_kernel(
    const unsigned short* __restrict__ x, const int* __restrict__ S,
    const unsigned short* __restrict__ Wb, const float* __restrict__ bias,
    float* __restrict__ y, int Nv, int KF, int elu_flag)
{
    constexpr int PAD = 40;
    __shared__ unsigned short Gs[2][256 * PAD];

    const int b    = blockIdx.x;
    const int n0   = blockIdx.y * 256;
    const int tid  = threadIdx.x;
    const int lane = tid & 63;
    const int wave = tid >> 6;
    const int wm   = wave * 64;
    const int l15  = lane & 15;
    const int quad = lane >> 4;
    const size_t xb = (size_t)b * Nv;
    const int nslab = KF >> 5;

    f32x4 acc[4][2];
#pragma unroll
    for (int t = 0; t < 4; ++t)
#pragma unroll
        for (int o = 0; o < 2; ++o) acc[t][o] = (f32x4){0.f, 0.f, 0.f, 0.f};

    auto gath = [&](int k0, bf16x8* g) {
        int n = n0 + tid;
        if (n < Nv) {
#pragma unroll
            for (int j = 0; j < 4; ++j) {
                int kf  = k0 + j * 8;
                int k   = kf >> LOGF;
                int f   = kf & ((1 << LOGF) - 1);
                int src = S[n * SPK + k];
                g[j] = *(const bf16x8*)(x + ((xb + src) << LOGF) + f);
            }
        } else {
#pragma unroll
            for (int j = 0; j < 4; ++j)
#pragma unroll
                for (int e = 0; e < 8; ++e) g[j][e] = 0;
        }
    };
    auto put = [&](int buf, const bf16x8* g) {
#pragma unroll
        for (int j = 0; j < 4; ++j)
            *(bf16x8*)&Gs[buf][tid * PAD + j * 8] = g[j];
    };
    auto wfrag = [&](int k0, int o16) {
        return *(const bf16x8*)(Wb + (size_t)(o16 * 16 + l15) * KF + k0 + quad * 8);
    };

    bf16x8 gcur[4], gnext[4];
    gath(0, gcur);
    put(0, gcur);
    __syncthreads();

    for (int s = 0; s < nslab; ++s) {
        const int cur = s & 1;
        const bool more = (s + 1) < nslab;
        if (more) gath((s + 1) * 32, gnext);
        bf16x8 wf0 = wfrag(s * 32, 0);
        bf16x8 wf1 = wfrag(s * 32, 1);
#pragma unroll
        for (int t = 0; t < 4; ++t) {
            bf16x8 a = *(const bf16x8*)&Gs[cur][(wm + t * 16 + l15) * PAD + quad * 8];
            acc[t][0] = __builtin_amdgcn_mfma_f32_16x16x32_bf16(a, wf0, acc[t][0], 0, 0, 0);
            acc[t][1] = __builtin_amdgcn_mfma_f32_16x16x32_bf16(a, wf1, acc[t][1], 0, 0, 0);
        }
        if (more) {
            put(cur ^ 1, gnext);
            __syncthreads();
        }
    }

    float bv0 = bias[l15];
    float bv1 = bias[16 + l15];
#pragma unroll
    for (int t = 0; t < 4; ++t)
#pragma unroll
        for (int reg = 0; reg < 4; ++reg) {
            int n = n0 + wm + t * 16 + quad * 4 + reg;
            if (n >= Nv) continue;
            float v0 = acc[t][0][reg] + bv0;
            float v1 = acc[t][1][reg] + bv1;
            if (elu_flag) {
                if (v0 <= 0.f) v0 = expm1f(v0);
                if (v1 <= 0.f) v1 = expm1f(v1);
            }
            if (n == Nv - 1) { v0 = 0.f; v1 = 0.f; }
            size_t off = ((size_t)b * Nv + n) * 32 + l15;
            y[off]      = v0;
            y[off + 16] = v1;
        }
}

// ---------------------------------------------------------------------------
// dsamp_mfma3: 128x128 tile MFMA resample. NT: non-temporal partial stores.
// D0/U0.
// ---------------------------------------------------------------------------
template<int OBF16, int NT>
__global__ __launch_bounds__(256) void dsamp_mfma3_kernel(
    const unsigned short* __restrict__ Ab, const unsigned short* __restrict__ Xt,
    void* __restrict__ Yv, int M, int Kp, int logF, int kchunk,
    int atomic_flag, int swz, size_t pstride)
{
    constexpr int PAD = 40;
    __shared__ unsigned short As[2][128 * PAD];
    __shared__ unsigned short Bs[2][128 * PAD];

    int bx = blockIdx.x, by = blockIdx.y, bz = blockIdx.z;
    if (swz) {
        const int gx = gridDim.x, gy = gridDim.y;
        const int total = gx * gy * gridDim.z;
        int bid = bx + gx * (by + gy * bz);
        const int chunk = total >> 3;
        int sid = (bid & 7) * chunk + (bid >> 3);
        bx = sid % gx; sid /= gx;
        by = sid % gy;
        bz = sid / gy;
    }

    const int fmask = (1 << logF) - 1;
    const int m0   = bx * 128;
    const int c0   = by * 128;
    const int kbeg = bz * kchunk;
    int kend = kbeg + kchunk; if (kend > Kp) kend = Kp;
    const int nslab = (kend - kbeg + 31) >> 5;
    const size_t zoff = (size_t)bz * pstride;

    const int tid  = threadIdx.x;
    const int lane = tid & 63;
    const int wave = tid >> 6;
    const int wm   = (wave >> 1) * 64;
    const int wn   = (wave & 1) * 64;
    const int l15  = lane & 15;
    const int quad = lane >> 4;

    const int s_row = tid >> 2;
    const int s_k8  = (tid & 3) * 8;

    f32x4 acc[4][4];
#pragma unroll
    for (int i = 0; i < 4; ++i)
#pragma unroll
        for (int j = 0; j < 4; ++j) acc[i][j] = (f32x4){0.f, 0.f, 0.f, 0.f};

    bf16x8 apre[2], bpre[2];

    auto loadAB = [&](int ko) {
        apre[0] = *(const bf16x8*)(Ab + (size_t)(m0 + s_row)      * Kp + ko + s_k8);
        apre[1] = *(const bf16x8*)(Ab + (size_t)(m0 + s_row + 64) * Kp + ko + s_k8);
        bpre[0] = *(const bf16x8*)(Xt + (size_t)(c0 + s_row)      * Kp + ko + s_k8);
        bpre[1] = *(const bf16x8*)(Xt + (size_t)(c0 + s_row + 64) * Kp + ko + s_k8);
    };
    auto stage = [&](int buf) {
        *(bf16x8*)&As[buf][s_row * PAD + s_k8]        = apre[0];
        *(bf16x8*)&As[buf][(s_row + 64) * PAD + s_k8] = apre[1];
        *(bf16x8*)&Bs[buf][s_row * PAD + s_k8]        = bpre[0];
        *(bf16x8*)&Bs[buf][(s_row + 64) * PAD + s_k8] = bpre[1];
    };

    loadAB(kbeg);
    stage(0);
    __syncthreads();

    for (int s = 0; s < nslab; ++s) {
        const int cur = s & 1;
        const bool more = (s + 1) < nslab;
        if (more) loadAB(kbeg + (s + 1) * 32);

        bf16x8 af[4], bfr[4];
#pragma unroll
        for (int t = 0; t < 4; ++t) {
            af[t]  = *(const bf16x8*)&As[cur][(wm + t * 16 + l15) * PAD + quad * 8];
            bfr[t] = *(const bf16x8*)&Bs[cur][(wn + t * 16 + l15) * PAD + quad * 8];
        }
#pragma unroll
        for (int tm = 0; tm < 4; ++tm)
#pragma unroll
            for (int tn = 0; tn < 4; ++tn)
                acc[tm][tn] = __builtin_amdgcn_mfma_f32_16x16x32_bf16(af[tm], bfr[tn], acc[tm][tn], 0, 0, 0);

        if (more) { stage(cur ^ 1); __syncthreads(); }
    }

#pragma unroll
    for (int tm = 0; tm < 4; ++tm)
#pragma unroll
        for (int tn = 0; tn < 4; ++tn)
#pragma unroll
            for (int reg = 0; reg < 4; ++reg) {
                int m  = m0 + wm + tm * 16 + quad * 4 + reg;
                int cc = c0 + wn + tn * 16 + l15;
                if (m < M) {
                    int bb = cc >> logF, f = cc & fmask;
                    size_t off = zoff + (((size_t)bb * M + m) << logF) + f;
                    float v = acc[tm][tn][reg];
                    if (OBF16)            ((unsigned short*)Yv)[off] = f2bf(v);
                    else if (atomic_flag) atomicAdd((float*)Yv + off, v);
                    else if (NT)          __builtin_nontemporal_store(v, (float*)Yv + off);
                    else                  ((float*)Yv)[off] = v;
                }
            }
}

// ---------------------------------------------------------------------------
// dsamp_mfma2: A pre-converted bf16; X fp32 staged to LDS. D1/U1/D2/U2.
// ---------------------------------------------------------------------------
template<int OBF16, int NT>
__global__ __launch_bounds__(256) void dsamp_mfma2_kernel(
    const unsigned short* __restrict__ Ap, const float* __restrict__ X,
    void* __restrict__ Yv, int M, int K, int Kp, int logF, int kchunk,
    int atomic_flag, size_t pstride)
{
    constexpr int PAD = 40;
    __shared__ unsigned short Xs[2][64 * PAD];

    const int fmask = (1 << logF) - 1;
    const int m0   = blockIdx.x * 64;
    const int c0   = blockIdx.y * 64;
    const int kbeg = blockIdx.z * kchunk;
    int kend = kbeg + kchunk; if (kend > K) kend = K;
    const int nslab = (kend - kbeg + 31) >> 5;
    const size_t zoff = (size_t)blockIdx.z * pstride;

    const int tid  = threadIdx.x;
    const int lane = tid & 63;
    const int wave = tid >> 6;
    const int wm   = (wave >> 1) * 32;
    const int wn   = (wave & 1) * 32;
    const int l15  = lane & 15;
    const int quad = lane >> 4;

    const int skk  = tid >> 4;
    const int scg  = (tid & 15) * 4;
    const int cB   = c0 + scg;
    const int xbb  = cB >> logF;
    const int xf   = cB & fmask;
    const size_t xrowbase = (((size_t)xbb * K) << logF) + xf;

    const int mA0 = m0 + wm + l15;
    const int mA1 = mA0 + 16;
    const int kaoff = quad * 8;

    f32x4 acc[2][2];
    acc[0][0] = acc[0][1] = acc[1][0] = acc[1][1] = (f32x4){0.f, 0.f, 0.f, 0.f};

    float4 xn0, xn1;
    bf16x8 ac0, ac1, an0, an1;

    {
        int k = kbeg + skk;
        xn0 = make_float4(0.f, 0.f, 0.f, 0.f);
        if (k < kend) xn0 = *(const float4*)(X + xrowbase + ((size_t)k << logF));
        k = kbeg + 16 + skk;
        xn1 = make_float4(0.f, 0.f, 0.f, 0.f);
        if (k < kend) xn1 = *(const float4*)(X + xrowbase + ((size_t)k << logF));
        int ka = kbeg + kaoff;
        ac0 = *(const bf16x8*)(Ap + (size_t)mA0 * Kp + ka);
        ac1 = *(const bf16x8*)(Ap + (size_t)mA1 * Kp + ka);
        unsigned short* p = &Xs[0][0];
        p[(scg + 0) * PAD + skk] = f2bf(xn0.x);
        p[(scg + 1) * PAD + skk] = f2bf(xn0.y);
        p[(scg + 2) * PAD + skk] = f2bf(xn0.z);
        p[(scg + 3) * PAD + skk] = f2bf(xn0.w);
        int kk1 = 16 + skk;
        p[(scg + 0) * PAD + kk1] = f2bf(xn1.x);
        p[(scg + 1) * PAD + kk1] = f2bf(xn1.y);
        p[(scg + 2) * PAD + kk1] = f2bf(xn1.z);
        p[(scg + 3) * PAD + kk1] = f2bf(xn1.w);
    }
    __syncthreads();

    for (int s = 0; s < nslab; ++s) {
        const int cur = s & 1;
        const bool more = (s + 1 < nslab);
        if (more) {
            int k0 = kbeg + (s + 1) * 32;
            int k = k0 + skk;
            xn0 = make_float4(0.f, 0.f, 0.f, 0.f);
            if (k < kend) xn0 = *(const float4*)(X + xrowbase + ((size_t)k << logF));
            k = k0 + 16 + skk;
            xn1 = make_float4(0.f, 0.f, 0.f, 0.f);
            if (k < kend) xn1 = *(const float4*)(X + xrowbase + ((size_t)k << logF));
            int ka = k0 + kaoff;
            an0 = *(const bf16x8*)(Ap + (size_t)mA0 * Kp + ka);
            an1 = *(const bf16x8*)(Ap + (size_t)mA1 * Kp + ka);
        }
        {
            const unsigned short* p = &Xs[cur][0];
            bf16x8 b0 = *(const bf16x8*)&p[(wn +      l15) * PAD + quad * 8];
            bf16x8 b1 = *(const bf16x8*)&p[(wn + 16 + l15) * PAD + quad * 8];
            acc[0][0] = __builtin_amdgcn_mfma_f32_16x16x32_bf16(ac0, b0, acc[0][0], 0, 0, 0);
            acc[0][1] = __builtin_amdgcn_mfma_f32_16x16x32_bf16(ac0, b1, acc[0][1], 0, 0, 0);
            acc[1][0] = __builtin_amdgcn_mfma_f32_16x16x32_bf16(ac1, b0, acc[1][0], 0, 0, 0);
            acc[1][1] = __builtin_amdgcn_mfma_f32_16x16x32_bf16(ac1, b1, acc[1][1], 0, 0, 0);
        }
        if (more) {
            unsigned short* q = &Xs[cur ^ 1][0];
            q[(scg + 0) * PAD + skk] = f2bf(xn0.x);
            q[(scg + 1) * PAD + skk] = f2bf(xn0.y);
            q[(scg + 2) * PAD + skk] = f2bf(xn0.z);
            q[(scg + 3) * PAD + skk] = f2bf(xn0.w);
            int kk1 = 16 + skk;
            q[(scg + 0) * PAD + kk1] = f2bf(xn1.x);
            q[(scg + 1) * PAD + kk1] = f2bf(xn1.y);
            q[(scg + 2) * PAD + kk1] = f2bf(xn1.z);
            q[(scg + 3) * PAD + kk1] = f2bf(xn1.w);
            __syncthreads();
            ac0 = an0; ac1 = an1;
        }
    }

#pragma unroll
    for (int tm = 0; tm < 2; ++tm)
#pragma unroll
        for (int tn = 0; tn < 2; ++tn)
#pragma unroll
            for (int reg = 0; reg < 4; ++reg) {
                int m  = m0 + wm + tm * 16 + quad * 4 + reg;
                int cc = c0 + wn + tn * 16 + l15;
                if (m < M) {
                    int bb = cc >> logF, f = cc & fmask;
                    size_t off = zoff + (((size_t)bb * M + m) << logF) + f;
                    float v = acc[tm][tn][reg];
                    if (OBF16)            ((unsigned short*)Yv)[off] = f2bf(v);
                    else if (atomic_flag) atomicAdd((float*)Yv + off, v);
                    else if (NT)          __builtin_nontemporal_store(v, (float*)Yv + off);
                    else                  ((float*)Yv)[off] = v;
                }
            }
}

// ---------------------------------------------------------------------------
// conv_gemm (fp32 gather). e0 only. Grid: (batch, mtile).
// ---------------------------------------------------------------------------
template<int MT, int OT>
__global__ __launch_bounds__(256) void conv_gemm_kernel(
    const float* __restrict__ x, const int* __restrict__ S,
    const float* __restrict__ W, const float* __restrict__ bias,
    float* __restrict__ y, int Nv, int logF, int O, int KF, int KFr,
    int elu_flag)
{
    constexpr int CT = OT / 4;
    constexpr int RT = 256 / CT;
    static_assert(RT * 4 == MT, "tile shape");
    __shared__ float Gs[32][MT];
    __shared__ float Ws[32][OT];

    const int b   = blockIdx.x;
    const int n0  = blockIdx.y * MT;
    const int tid = threadIdx.x;
    const int cx  = tid % CT;
    const int ry  = tid / CT;
    const int r0  = ry * 4;
    const int o0  = cx * 4;
    const int fmask = (1 << logF) - 1;
    const size_t xb = (size_t)b * Nv;

    float acc[4][4];
#pragma unroll
    for (int i = 0; i < 4; ++i)
#pragma unroll
        for (int j = 0; j < 4; ++j) acc[i][j] = 0.f;

    for (int k0 = 0; k0 < KF; k0 += 32) {
        constexpr int GSLOTS = MT * 8;
#pragma unroll
        for (int i = 0; i < GSLOTS / 256; ++i) {
            int idx = tid + i * 256;
            int r   = idx & (MT - 1);
            int jg  = idx / MT;
            int j0  = jg * 4;
            int n   = n0 + r;
            int kf  = k0 + j0;
            float4 v = make_float4(0.f, 0.f, 0.f, 0.f);
            if (n < Nv && kf < KFr) {
                int k   = kf >> logF;
                int f   = kf & fmask;
                int src = S[n * SPK + k];
                v = *(const float4*)(x + ((xb + src) << logF) + f);
            }
            Gs[j0 + 0][r] = v.x; Gs[j0 + 1][r] = v.y;
            Gs[j0 + 2][r] = v.z; Gs[j0 + 3][r] = v.w;
        }
        constexpr int WSLOTS = OT * 8;
#pragma unroll
        for (int i = 0; i < (WSLOTS + 255) / 256; ++i) {
            int idx = tid + i * 256;
            if (WSLOTS >= 256 || idx < WSLOTS) {
                int o  = idx & (OT - 1);
                int jg = idx / OT;
                int j0 = jg * 4;
                float4 v = *(const float4*)(W + (size_t)o * KF + k0 + j0);
                Ws[j0 + 0][o] = v.x; Ws[j0 + 1][o] = v.y;
                Ws[j0 + 2][o] = v.z; Ws[j0 + 3][o] = v.w;
            }
        }
        __syncthreads();
#pragma unroll
        for (int kk = 0; kk < 32; ++kk) {
            float4 g = *(const float4*)&Gs[kk][r0];
            float4 w = *(const float4*)&Ws[kk][o0];
            acc[0][0] += g.x * w.x; acc[0][1] += g.x * w.y; acc[0][2] += g.x * w.z; acc[0][3] += g.x * w.w;
            acc[1][0] += g.y * w.x; acc[1][1] += g.y * w.y; acc[1][2] += g.y * w.z; acc[1][3] += g.y * w.w;
            acc[2][0] += g.z * w.x; acc[2][1] += g.z * w.y; acc[2][2] += g.z * w.z; acc[2][3] += g.z * w.w;
            acc[3][0] += g.w * w.x; acc[3][1] += g.w * w.y; acc[3][2] += g.w * w.z; acc[3][3] += g.w * w.w;
        }
        __syncthreads();
    }

    float4 bv = *(const float4*)(bias + o0);
#pragma unroll
    for (int i = 0; i < 4; ++i) {
        int n = n0 + r0 + i;
        if (n >= Nv) continue;
        float v0 = acc[i][0] + bv.x;
        float v1 = acc[i][1] + bv.y;
        float v2 = acc[i][2] + bv.z;
        float v3 = acc[i][3] + bv.w;
        if (elu_flag) {
            v0 = v0 > 0.f ? v0 : expm1f(v0);
            v1 = v1 > 0.f ? v1 : expm1f(v1);
            v2 = v2 > 0.f ? v2 : expm1f(v2);
            v3 = v3 > 0.f ? v3 : expm1f(v3);
        }
        if (n == Nv - 1) { v0 = v1 = v2 = v3 = 0.f; }
        *(float4*)(y + ((size_t)b * Nv + n) * O + o0) = make_float4(v0, v1, v2, v3);
    }
}

// ---------------------------------------------------------------------------
// VALU down/up-sample (d3/u3 only). OBF16: emit bf16 output.
// ---------------------------------------------------------------------------
template<int OBF16>
__global__ __launch_bounds__(256) void dsamp_kernel(
    const float* __restrict__ A, const float* __restrict__ X,
    void* __restrict__ Yv, int M, int N, int F)
{
    __shared__ float As[16][68];
    __shared__ float Xs[16][64];

    const int m0  = blockIdx.x * 64;
    const int c0  = blockIdx.y * 64;
    const int tid = threadIdx.x;
    const int tx  = tid & 15;
    const int ty  = tid >> 4;

    float acc[4][4];
#pragma unroll
    for (int i = 0; i < 4; ++i)
#pragma unroll
        for (int j = 0; j < 4; ++j) acc[i][j] = 0.f;

    for (int k0 = 0; k0 < N; k0 += 16) {
#pragma unroll
        for (int p = 0; p < 4; ++p) {
            int r  = (tid >> 4) + p * 16;
            int kk = tid & 15;
            int m  = m0 + r;
            int n  = k0 + kk;
            float v = 0.f;
            if (m < M && n < N) v = A[(size_t)m * N + n];
            As[kk][r] = v;
        }
        {
            int kk = tid >> 4;
            int cc = (tid & 15) * 4;
            int n  = k0 + kk;
            float4 v = make_float4(0.f, 0.f, 0.f, 0.f);
            if (n < N) {
                int c  = c0 + cc;
                int bb = c / F;
                int f  = c - bb * F;
                v = *(const float4*)(X + ((size_t)bb * N + n) * F + f);
            }
            *(float4*)&Xs[kk][cc] = v;
        }
        __syncthreads();
#pragma unroll
        for (int kk = 0; kk < 16; ++kk) {
            float4 av = *(const float4*)&As[kk][ty * 4];
            float4 xv = *(const float4*)&Xs[kk][tx * 4];
            acc[0][0] += av.x * xv.x; acc[0][1] += av.x * xv.y; acc[0][2] += av.x * xv.z; acc[0][3] += av.x * xv.w;
            acc[1][0] += av.y * xv.x; acc[1][1] += av.y * xv.y; acc[1][2] += av.y * xv.z; acc[1][3] += av.y * xv.w;
            acc[2][0] += av.z * xv.x; acc[2][1] += av.z * xv.y; acc[2][2] += av.z * xv.z; acc[2][3] += av.z * xv.w;
            acc[3][0] += av.w * xv.x; acc[3][1] += av.w * xv.y; acc[3][2] += av.w * xv.z; acc[3][3] += av.w * xv.w;
        }
        __syncthreads();
    }

    const int cbase = c0 + tx * 4;
    const int bb = cbase / F;
    const int f  = cbase - bb * F;
#pragma unroll
    for (int i = 0; i < 4; ++i) {
        int m = m0 + ty * 4 + i;
        if (m < M) {
            size_t off = ((size_t)bb * M + m) * F + f;
            if (OBF16) {
                bf16x4 v;
                v[0] = (short)f2bf(acc[i][0]); v[1] = (short)f2bf(acc[i][1]);
                v[2] = (short)f2bf(acc[i][2]); v[3] = (short)f2bf(acc[i][3]);
                *(bf16x4*)((unsigned short*)Yv + off) = v;
            } else {
                *(float4*)((float*)Yv + off) =
                    make_float4(acc[i][0], acc[i][1], acc[i][2], acc[i][3]);
            }
        }
    }
}

// ---------------------------------------------------------------------------
// fc_wave: one 64-lane wave per output element.
// ---------------------------------------------------------------------------
__global__ __launch_bounds__(256) void fc_wave_kernel(
    const float* __restrict__ in, const float* __restrict__ W,
    const float* __restrict__ bias, float* __restrict__ out,
    int In, int O, int dup)
{
    const int gw   = blockIdx.x * 4 + (threadIdx.x >> 6);
    const int lane = threadIdx.x & 63;
    const int b = gw / O;
    const int o = gw - b * O;
    const float* xr = in + (size_t)b * In;
    float acc = 0.f;
    if (dup) {
        const float* wr = W + (size_t)o * (2 * In);
        for (int k = lane; k < In; k += 64)
            acc += xr[k] * (wr[k] + wr[In + k]);
    } else {
        const float* wr = W + (size_t)o * In;
        for (int k = lane; k < In; k += 64)
            acc += xr[k] * wr[k];
    }
#pragma unroll
    for (int off = 32; off > 0; off >>= 1)
        acc += __shfl_down(acc, off, 64);
    if (lane == 0) out[(size_t)b * O + o] = acc + bias[o];
}

// ---------------------------------------------------------------------------
// Transpose-convert: x [b][k][f] fp32 -> xt [c][k] bf16, c = b*F+f, stride Kp.
// ---------------------------------------------------------------------------
__global__ __launch_bounds__(256) void xpose_bf16_kernel(
    const float* __restrict__ x, unsigned short* __restrict__ xt,
    int K, int Kp, int logF)
{
    const int c  = blockIdx.y * 256 + threadIdx.x;
    const int k0 = blockIdx.x * 8;
    const int bb = c >> logF;
    const int f  = c & ((1 << logF) - 1);
    const float* src = x + (((size_t)bb * K) << logF) + f;
    bf16x8 r;
#pragma unroll
    for (int j = 0; j < 8; ++j) {
        int k = k0 + j;
        float v = (k < K) ? src[(size_t)k << logF] : 0.f;
        r[j] = (short)f2bf(v);
    }
    *(bf16x8*)(xt + (size_t)c * Kp + k0) = r;
}

// ---------------------------------------------------------------------------
// pad_x4 / extract helpers.
// ---------------------------------------------------------------------------
__global__ __launch_bounds__(256) void pad_x4_kernel(
    const float* __restrict__ x, float* __restrict__ xp, int n)
{
    int i = blockIdx.x * 256 + threadIdx.x;
    if (i < n) {
        int f = i & 3, nb = i >> 2;
        xp[i] = (f < 3) ? x[nb * 3 + f] : 0.f;
    }
}
__global__ __launch_bounds__(256) void extract_add_kernel(
    const float* __restrict__ cp, const float* __restrict__ t,
    float* __restrict__ o0, float* __restrict__ o1, int n)
{
    int i = blockIdx.x * 256 + threadIdx.x;
    if (i < n) {
        int f = i % 3, nb = i / 3;
        float v = cp[(size_t)nb * 16 + f];
        o0[i] = v;
        o1[i] = v + t[i];
    }
}

// ---------------------------------------------------------------------------

static inline int ilog2(int v) { int l = 0; while ((1 << l) < v) ++l; return l; }

static inline void a_bf16_launch(const float* A, unsigned short* Ap, int M, int K,
                                 int Mp, int Kp, hipStream_t s)
{
    int total = Mp * (Kp >> 3);
    a_bf16_pad_kernel<<<(total + 255) / 256, 256, 0, s>>>(A, Ap, M, K, Kp, total);
}

template<int OBF16, int NT>
static inline void dsamp_mfma2_launch(const unsigned short* Ap, const float* X,
                                      void* Y, int M, int K, int Kp, int F,
                                      int ks, int partial, hipStream_t s)
{
    int kchunk = (K + ks - 1) / ks;
    kchunk = (kchunk + 31) & ~31;
    int ksz = (K + kchunk - 1) / kchunk;
    int atomic = (ksz > 1 && !partial) ? 1 : 0;
    size_t pstride = (partial && ksz > 1) ? (size_t)BATCH * M * F : 0;
    dim3 grid((M + 63) / 64, F, ksz);
    dsamp_mfma2_kernel<OBF16, NT><<<grid, 256, 0, s>>>(Ap, X, Y, M, K, Kp, ilog2(F),
                                                       kchunk, atomic, pstride);
}

template<int OBF16, int NT>
static inline void dsamp_mfma3_launch(const unsigned short* Ab, const unsigned short* Xt,
                                      void* Y, int M, int Kp, int F,
                                      int ks, int partial, hipStream_t s)
{
    int slabs = Kp >> 5;
    int kchunk = ((slabs + ks - 1) / ks) * 32;
    int ksz = (Kp + kchunk - 1) / kchunk;
    int gx = (M + 127) / 128, gy = (BATCH * F) / 128;
    int total = gx * gy * ksz;
    int swz = ((total & 7) == 0) ? 1 : 0;
    int atomic = (ksz > 1 && !partial) ? 1 : 0;
    size_t pstride = (partial && ksz > 1) ? (size_t)BATCH * M * F : 0;
    dim3 grid(gx, gy, ksz);
    dsamp_mfma3_kernel<OBF16, NT><<<grid, 256, 0, s>>>(Ab, Xt, Y, M, Kp, ilog2(F),
                                                       kchunk, atomic, swz, pstride);
}

template<int OBF16>
static inline void dsamp_launch(const float* A, const float* X, void* Y,
                                int M, int N, int F, hipStream_t s)
{
    dim3 grid((M + 63) / 64, F);
    dsamp_kernel<OBF16><<<grid, 256, 0, s>>>(A, X, Y, M, N, F);
}

extern "C" void kernel_launch(void* const* d_in, const int* in_sizes, int n_in,
                              void* d_out, int out_size, void* d_ws, size_t ws_size,
                              hipStream_t stream)
{
    const float* x_talking = (const float*)d_in[0];
    const float* templ     = (const float*)d_in[1];
    const float* D0 = (const float*)d_in[2];
    const float* U0 = (const float*)d_in[3];
    const float* D1 = (const float*)d_in[4];
    const float* U1 = (const float*)d_in[5];
    const float* D2 = (const float*)d_in[6];
    const float* U2 = (const float*)d_in[7];
    const float* D3 = (const float*)d_in[8];
    const float* U3 = (const float*)d_in[9];
    const float* enc_w0 = (const float*)d_in[10]; const float* enc_b0 = (const float*)d_in[11];
    const float* enc_w1 = (const float*)d_in[12]; const float* enc_b1 = (const float*)d_in[13];
    const float* enc_w2 = (const float*)d_in[14]; const float* enc_b2 = (const float*)d_in[15];
    const float* enc_w3 = (const float*)d_in[16]; const float* enc_b3 = (const float*)d_in[17];
    const float* fc_enc_w = (const float*)d_in[18]; const float* fc_enc_b = (const float*)d_in[19];
    const float* fc_dec_w = (const float*)d_in[20]; const float* fc_dec_b = (const float*)d_in[21];
    const float* dec_w0 = (const float*)d_in[22]; const float* dec_b0 = (const float*)d_in[23];
    const float* dec_w1 = (const float*)d_in[24]; const float* dec_b1 = (const float*)d_in[25];
    const float* dec_w2 = (const float*)d_in[26]; const float* dec_b2 = (const float*)d_in[27];
    const float* dec_w3 = (const float*)d_in[28]; const float* dec_b3 = (const float*)d_in[29];
    const float* dec_w4 = (const float*)d_in[30]; const float* dec_b4 = (const float*)d_in[31];
    const int* S0 = (const int*)d_in[32];
    const int* S1 = (const int*)d_in[33];
    const int* S2 = (const int*)d_in[34];
    const int* S3 = (const int*)d_in[35];

    float* bufA = (float*)d_ws;            // 10,289,152 floats (41.2 MB)
    float* bufB = bufA + 10289152;         // 5,144,576 floats (20.6 MB)

    float* out0 = (float*)d_out;           // 964,608 floats
    float* out1 = out0 + 964608;

    // ---- workspace aliases (lifetimes audited per stream order) ----
    // bufA tail [10,160,000..10,289,152): weights, written once by prep,
    // NEVER clobbered (max other bufA write ends at 10,154,800 = D1b end).
    unsigned short* Xt_e0 = (unsigned short*)(bufB + 1290240);
    unsigned short* Xt_c2 = (unsigned short*)bufB;
    unsigned short* U0b   = (unsigned short*)(bufB + 1400000);
    unsigned short* Wb_e2 = (unsigned short*)(bufB + 4700000);
    unsigned short* Wb_e3 = (unsigned short*)(bufB + 4715000);
    unsigned short* Wb_c0 = (unsigned short*)(bufB + 4765000);
    unsigned short* Wb_c1 = (unsigned short*)(bufB + 4815000);
    unsigned short* D2b   = (unsigned short*)(bufB + 4830000);
    unsigned short* U2b   = (unsigned short*)(bufB + 4860000);
    float* xpad   = bufA + 5200000;
    unsigned short* D0b   = (unsigned short*)(bufA + 6700000);   // ends 9,915,360
    unsigned short* D1b   = (unsigned short*)(bufA + 9950000);   // ends 10,154,800
    unsigned short* U1b   = (unsigned short*)(bufA + 4000000);
    unsigned short* Wb_e1 = (unsigned short*)(bufA + 10160000);
    unsigned short* Wb_c2 = (unsigned short*)(bufA + 10170000);
    unsigned short* Wfs_c3 = (unsigned short*)(bufA + 10180000);
    unsigned short* Wfs_c4 = (unsigned short*)(bufA + 10185000);
    float* BpC4   = bufA + 10190000;
    float* WpE0   = bufA + 10195000;
    float*          Pd0   = bufA;                                // 5 partials
    unsigned short* Xb_e1 = (unsigned short*)bufB;               // d0-out bf16
    float*          Pd1   = bufA + 5200000;                      // 4 partials
    unsigned short* Xb_e2   = (unsigned short*)(bufA + 2000000);
    float*          Pd2   = bufB;                                // 4 partials
    unsigned short* Xb_e3   = (unsigned short*)(bufA + 2000000);
    unsigned short* Xb_c2in = (unsigned short*)(bufA + 2600000);
    unsigned short* Xb_c3n  = (unsigned short*)bufA;             // u0 bf16 out
    unsigned short* Xb_c4   = (unsigned short*)(bufA + 5200000);

    // ---- fused weight prep (1 launch replaces 11) ----
    prep_weights_kernel<<<(PREP_TOTAL + 255) / 256, 256, 0, stream>>>(
        enc_w0, enc_w1, enc_w2, enc_w3, dec_w0, dec_w1, dec_w2, dec_w3,
        dec_w4, dec_b4, WpE0, Wb_e1, Wb_c2, Wb_e2, Wb_e3, Wb_c0, Wb_c1,
        Wfs_c3, Wfs_c4, BpC4);
    pad_x4_kernel<<<5024, 256, 0, stream>>>(x_talking, xpad, 1286144);
    a_bf16_launch(D0, D0b, 1257, 5024, 1280, 5024, stream);
    a_bf16_launch(D1, D1b, 315, 1257, 320, 1280, stream);
    a_bf16_launch(D2, D2b, 80, 315, 128, 320, stream);
    a_bf16_launch(U2, U2b, 315, 80, 320, 96, stream);

    // ---- encoder ----
    {   // e0: F=4(pad), KF=64 (KFr=48), O=16, fp32 (first-layer precision)
        dim3 grid(BATCH, (5024 + 255) / 256);
        conv_gemm_kernel<256, 16><<<grid, 256, 0, stream>>>(
            xpad, S0, WpE0, enc_b0, bufA, 5024, 2, 16, 64, 48, 1);
    }
    xpose_bf16_kernel<<<dim3(628, 4), 256, 0, stream>>>(bufA, Xt_e0, 5024, 5024, 4);
    // d0: ks=5 partials, non-temporal stores -> Pd0; reduce -> Xb_e1
    dsamp_mfma3_launch<0, 1>(D0b, Xt_e0, Pd0, 1257, 5024, 16, 5, 1, stream);
    reducep_bf16_kernel<<<629, 256, 0, stream>>>(Pd0, 1287168, Xb_e1, 160896, 5);
    a_bf16_launch(U0, U0b, 5024, 1257, 5120, 1280, stream);
    a_bf16_launch(U1, U1b, 1257, 315, 1280, 320, stream);
    {   // e1: MFMA conv, F=16, O=32, ELU -> bufA [64,1257,32] fp32
        dim3 grid(BATCH, (1257 + 255) / 256);
        conv_mfma32_kernel<4><<<grid, 256, 0, stream>>>(
            Xb_e1, S1, Wb_e1, enc_b1, bufA, 1257, 192, 1);
    }
    // d1: ks=4 partials (nt) -> Pd1; reduce -> Xb_e2
    dsamp_mfma2_launch<0, 1>(D1b, bufA, Pd1, 315, 1257, 1280, 32, 4, 1, stream);
    reducep_bf16_kernel<<<315, 256, 0, stream>>>(Pd1, 645120, Xb_e2, 80640, 4);
    {   // e2: wave-MFMA conv, F=32, O=64 -> bufA fp32 [64,315,64]
        dim3 grid((315 + 15) / 16, 64 / 16, BATCH);
        conv_wmfma_kernel<5, 0><<<grid, 64, 0, stream>>>(
            Xb_e2, S2, Wb_e2, enc_b2, bufA, 315, 64, 1, 0);
    }
    // d2: ks=4 partials (nt) -> Pd2; reduce -> Xb_e3
    dsamp_mfma2_launch<0, 1>(D2b, bufA, Pd2, 80, 315, 320, 64, 4, 1, stream);
    reducep_bf16_kernel<<<160, 256, 0, stream>>>(Pd2, 327680, Xb_e3, 40960, 4);
    {   // e3: wave-MFMA conv, F=64, O=128 -> bufA fp32 [64,80,128]
        dim3 grid((80 + 15) / 16, 128 / 16, BATCH);
        conv_wmfma_kernel<6, 0><<<grid, 64, 0, stream>>>(
            Xb_e3, S3, Wb_e3, enc_b3, bufA, 80, 128, 1, 0);
    }
    dsamp_launch<0>(D3, bufA, bufB, 21, 80, 128, stream);                       // d3 fp32

    fc_wave_kernel<<<dim3((BATCH * 128) / 4), 256, 0, stream>>>(bufB, fc_enc_w, fc_enc_b, bufA, 2688, 128, 0);
    fc_wave_kernel<<<dim3((BATCH * 2688) / 4), 256, 0, stream>>>(bufA, fc_dec_w, fc_dec_b, bufB, 128, 2688, 1);

    // ---- decoder ----
    dsamp_launch<1>(U3, bufB, bufA, 80, 21, 128, stream);                       // u3 -> bf16
    {   // c0: wave-MFMA conv, F=128, O=64 -> bufB fp32 [64,80,64]
        dim3 grid((80 + 15) / 16, 64 / 16, BATCH);
        conv_wmfma_kernel<7, 0><<<grid, 64, 0, stream>>>(
            (const unsigned short*)bufA, S3, Wb_c0, dec_b0, bufB, 80, 64, 1, 0);
    }
    // u2: MFMA path, ks=1, bf16 direct -> bufA [64,315,64] bf16
    dsamp_mfma2_launch<1, 0>(U2b, bufB, bufA, 315, 80, 96, 64, 1, 0, stream);
    {   // c1: wave-MFMA conv, F=64, O=32 -> bufB fp32 [64,315,32]
        dim3 grid((315 + 15) / 16, 32 / 16, BATCH);
        conv_wmfma_kernel<6, 0><<<grid, 64, 0, stream>>>(
            (const unsigned short*)bufA, S2, Wb_c1, dec_b1, bufB, 315, 32, 1, 0);
    }
    // u1: ks=1, bf16 direct out -> Xb_c2in
    dsamp_mfma2_launch<1, 0>(U1b, bufB, Xb_c2in, 1257, 315, 320, 32, 1, 0, stream);
    {   // c2: MFMA conv, F=32, O=32, ELU -> bufA [64,1257,32] fp32
        dim3 grid(BATCH, (1257 + 255) / 256);
        conv_mfma32_kernel<5><<<grid, 256, 0, stream>>>(
            Xb_c2in, S1, Wb_c2, dec_b2, bufA, 1257, 384, 1);
    }
    xpose_bf16_kernel<<<dim3(160, 8), 256, 0, stream>>>(bufA, Xt_c2, 1257, 1280, 5);
    // u0: ks=1, bf16 direct out -> Xb_c3n, XCD-swz
    dsamp_mfma3_launch<1, 0>(U0b, Xt_c2, Xb_c3n, 5024, 1280, 32, 1, 0, stream);

    {   // c3: coalesced-gather MFMA conv, F=32, O=16, ELU; bf16 out [XCD-swz]
        dim3 grid(5024 / 16, 1, BATCH);
        conv_cmfma_kernel<5, 1><<<grid, 64, 0, stream>>>(
            Xb_c3n, S0, Wfs_c3, dec_b3, (void*)Xb_c4, 5024, 1, 1);
    }
    {   // c4: coalesced-gather MFMA conv, F=16, O=16(pad), identity [XCD-swz]
        dim3 grid(5024 / 16, 1, BATCH);
        conv_cmfma_kernel<4, 0><<<grid, 64, 0, stream>>>(
            Xb_c4, S0, Wfs_c4, BpC4, (void*)bufB, 5024, 0, 1);
    }
    extract_add_kernel<<<(964608 + 255) / 256, 256, 0, stream>>>(bufB, templ, out0, out1, 964608);
}